// Round 8
// baseline (604.976 us; speedup 1.0000x reference)
//
#include <hip/hip_runtime.h>
#include <hip/hip_bf16.h>

#define N_NODES 100000
#define R_REL   8
#define E_EDGES 800000
#define D_FEAT  128
#define B_BASES 4
#define RN      (R_REL * N_NODES)
#define RE      (R_REL * E_EDGES)          // 6.4M edges

// radix partition: 784 coarse buckets of 128 dst nodes each
#define NBKT    784
#define BKT_CAP 9216                       // mean 8163, +11 sigma slack
#define P1_TPB  256
#define P1_EPT  32
#define P1_CHUNK (P1_TPB * P1_EPT)         // 8192 edges / WG
#define P1_NWG  ((RE + P1_CHUNK - 1) / P1_CHUNK)   // 782

// agg: 4 sub-buckets of 32 dst nodes per coarse bucket
#define SUB_PER_BKT 4
#define SGRID   (NBKT * SUB_PER_BKT)       // 3136
#define SUBCAP  2816                       // mean 2041, +17 sigma slack

#define NXW  (N_NODES * 64)                // xcvt items
#define NW1  (128 * 640)                   // wcvt items
#define NW2  (2 * 128 * 128)               // wcvt2 items

typedef __attribute__((ext_vector_type(8))) short short8;
typedef __attribute__((ext_vector_type(4))) float floatx4;

// ---- fused prep: xcvt + wcvt + wcvt2 + cursor init in ONE launch ----------
__global__ __launch_bounds__(256) void prep_kernel(
    const float* __restrict__ x, uint* __restrict__ xb,
    const float* __restrict__ bases, const float* __restrict__ loopw,
    unsigned short* __restrict__ wT,
    const float* __restrict__ ngnn_w, unsigned short* __restrict__ wT2,
    int* __restrict__ gcursor, int do_x) {
    int idx = blockIdx.x * 256 + threadIdx.x;
    if (do_x) {
        if (idx < NXW) {                       // x (fp32) -> xb (bf162 pairs)
            float2 v = *(const float2*)(x + 2 * (size_t)idx);
            __hip_bfloat162 h = __float22bfloat162_rn(v);
            xb[idx] = *(uint*)&h;
            return;
        }
        idx -= NXW;
    }
    if (idx < NW1) {                           // wT[n][k]
        int n = idx / 640, k = idx % 640;
        float v = (k < 512) ? bases[(size_t)k * 128 + n]
                            : loopw[(size_t)(k - 512) * 128 + n];
        __hip_bfloat16 h = __float2bfloat16(v);
        wT[idx] = *(unsigned short*)&h;
        return;
    }
    idx -= NW1;
    if (idx < NW2) {                           // wT2[l][n][k]
        int l = idx >> 14, rem = idx & 16383;
        int n = rem >> 7, k = rem & 127;
        float v = ngnn_w[(size_t)l * 16384 + (size_t)k * 128 + n];
        __hip_bfloat16 h = __float2bfloat16(v);
        wT2[idx] = *(unsigned short*)&h;
        return;
    }
    idx -= NW2;
    if (idx < NBKT) gcursor[idx] = idx * BKT_CAP;
}

// ---- pass 1: partition edges into coarse dst-buckets (coalesced writes) ---
// record = src(17b) | dst_low(7b)<<17 | r(3b)<<24
__global__ __launch_bounds__(256) void p1_kernel(
    const int* __restrict__ src, const int* __restrict__ dst,
    int* __restrict__ gcursor, int* __restrict__ ebuf2) {
    __shared__ int hist[NBKT];
    __shared__ int cnt2[NBKT];
    __shared__ int basebkt[NBKT];
    __shared__ int lofs[NBKT];
    __shared__ int aux[256];
    __shared__ int recs[P1_CHUNK];           // 32 KB
    __shared__ unsigned short bb[P1_CHUNK];  // 16 KB
    int t = threadIdx.x;
    for (int i = t; i < NBKT; i += 256) { hist[i] = 0; cnt2[i] = 0; }
    __syncthreads();

    int e0 = blockIdx.x * P1_CHUNK;
    int rec[P1_EPT];
    int bkt[P1_EPT];
#pragma unroll
    for (int i = 0; i < P1_EPT; ++i) {
        int e = e0 + i * P1_TPB + t;         // coalesced
        if (e < RE) {
            int d = dst[e];
            int s = src[e];
            int r = e / E_EDGES;             // magic-mul division
            bkt[i] = d >> 7;
            rec[i] = s | ((d & 127) << 17) | (r << 24);
            atomicAdd(&hist[bkt[i]], 1);     // native int ds_add
        } else bkt[i] = -1;
    }
    __syncthreads();

    // exclusive scan of hist[784]: 4 consecutive per thread + Hillis-Steele
    int k0 = t * 4;
    int c0 = (k0 + 0 < NBKT) ? hist[k0 + 0] : 0;
    int c1 = (k0 + 1 < NBKT) ? hist[k0 + 1] : 0;
    int c2 = (k0 + 2 < NBKT) ? hist[k0 + 2] : 0;
    int c3 = (k0 + 3 < NBKT) ? hist[k0 + 3] : 0;
    int s1 = c0 + c1, s2 = s1 + c2, s3 = s2 + c3;
    aux[t] = s3;
    __syncthreads();
    int vv = s3;
    for (int off = 1; off < 256; off <<= 1) {
        int yv = (t >= off) ? aux[t - off] : 0;
        __syncthreads();
        vv += yv;
        aux[t] = vv;
        __syncthreads();
    }
    int total = aux[255];
    int texcl = vv - s3;
    if (k0 + 0 < NBKT) lofs[k0 + 0] = texcl;
    if (k0 + 1 < NBKT) lofs[k0 + 1] = texcl + c0;
    if (k0 + 2 < NBKT) lofs[k0 + 2] = texcl + s1;
    if (k0 + 3 < NBKT) lofs[k0 + 3] = texcl + s2;
    __syncthreads();
    for (int i = t; i < NBKT; i += 256) {
        int hv = hist[i];
        basebkt[i] = (hv > 0) ? atomicAdd(&gcursor[i], hv) : 0;
    }
    __syncthreads();

    // reorder records into bucket-contiguous LDS slots
#pragma unroll
    for (int i = 0; i < P1_EPT; ++i) {
        if (bkt[i] >= 0) {
            int p = lofs[bkt[i]] + atomicAdd(&cnt2[bkt[i]], 1);
            recs[p] = rec[i];
            bb[p] = (unsigned short)bkt[i];
        }
    }
    __syncthreads();

    // writeout: consecutive i are mostly same-bucket runs
    for (int i = t; i < total; i += 256) {
        int b = bb[i];
        int p2 = basebkt[b] + (i - lofs[b]);
        if (p2 < (b + 1) * BKT_CAP) ebuf2[p2] = recs[i];
    }
}

// ---- fused sort+gather v6: half-wave split gather ------------------------
// 512 thr (8 waves), 4 WGs/CU (~25 KB LDS). id = sub*784 + bucket: the 4
// sub-WGs of one bucket are congruent mod 8 (784 % 8 == 0) -> same XCD.
// Gather: each wave splits into two independent 32-lane halves; each half
// owns 2 nodes and walks its own (node,r) segments with uint2 loads
// (32 lanes x 8 B = 256 B row coverage). Doubles concurrent segments per
// wave (latency hiding), halves load instructions per edge, no cross-lane
// shuffles, no masked bogus loads, stores stay 256 B-contiguous per half.
template <bool XB>
__global__ __launch_bounds__(512, 8) void agg3_kernel(
    const float* __restrict__ x,
    const uint*  __restrict__ xb,          // [N][64] bf162 pairs
    const int*   __restrict__ gcursor,
    const int*   __restrict__ ebuf2,
    const float* __restrict__ w_comp,
    __hip_bfloat162* __restrict__ y) {     // [N][256] bf162
    __shared__ int raw[SUBCAP];            // 11 KB
    __shared__ int sorted[SUBCAP];         // 11 KB (head doubles as scan aux)
    __shared__ int cursors[256];
    __shared__ int segbeg[256];
    __shared__ int nraw;
    const int t = threadIdx.x;
    const int bucket = blockIdx.x % NBKT;  // co-XCD mapping for the 4 sub-WGs
    const int sub    = blockIdx.x / NBKT;

    int cnt = gcursor[bucket] - bucket * BKT_CAP;
    if (cnt > BKT_CAP) cnt = BKT_CAP;
    const int* brec = ebuf2 + (size_t)bucket * BKT_CAP;
    if (t < 256) cursors[t] = 0;
    if (t == 0) nraw = 0;
    __syncthreads();

    const int lane = t & 63;
    const unsigned long long lmask = (1ull << lane) - 1ull;

    // single global pass: compact matching records into raw[] + histogram
    for (int i0 = 0; i0 < cnt; i0 += 512) {
        int i = i0 + t;
        int rec = (i < cnt) ? brec[i] : 0;
        bool match = (i < cnt) && ((((rec >> 17) & 127) >> 5) == sub);
        unsigned long long mask = __ballot(match);
        int base = 0;
        if (lane == 0) base = atomicAdd(&nraw, (int)__popcll(mask));
        base = __shfl(base, 0);
        if (match) {
            int p = base + (int)__popcll(mask & lmask);
            if (p < SUBCAP) {
                raw[p] = rec;
                int key = ((rec >> 17) & 31) * 8 + ((rec >> 24) & 7);
                atomicAdd(&cursors[key], 1);
            }
        }
    }
    __syncthreads();
    int n = nraw; if (n > SUBCAP) n = SUBCAP;

    // exclusive scan of 256 degrees (aux aliases sorted[0..511])
    int deg = (t < 256) ? cursors[t] : 0;
    int* aux = sorted;
    aux[t] = deg;
    __syncthreads();
    int vv = deg;
    for (int off = 1; off < 256; off <<= 1) {
        int yv = (t >= off && t < 256) ? aux[t - off] : 0;
        __syncthreads();
        vv += yv;
        aux[t] = vv;
        __syncthreads();
    }
    if (t < 256) {
        cursors[t] = vv - deg;
        segbeg[t]  = vv - deg;
    }
    __syncthreads();

    // in-LDS scatter to sorted order (src ids only)
    for (int i = t; i < n; i += 512) {
        int rec = raw[i];
        int key = ((rec >> 17) & 31) * 8 + ((rec >> 24) & 7);
        int pos = atomicAdd(&cursors[key], 1);   // ds_add_rtn_u32
        sorted[pos] = rec & 0x1FFFF;
    }
    __syncthreads();

    const int wid = t >> 6;
    if (XB) {
        // half-wave gather: half owns 2 nodes; lane covers bf162 pairs
        // (2hl, 2hl+1) of the node row via one uint2 load per edge.
        const int half = lane >> 5;
        const int hl   = lane & 31;
        const uint2* xb2 = (const uint2*)xb;   // [N][32]
        for (int np = 0; np < 2; ++np) {
            int nl = wid * 4 + half * 2 + np;  // 0..31 within sub-bucket
            int node = bucket * 128 + sub * 32 + nl;
            int key0 = nl * 8;
            float4 acc[B_BASES];
#pragma unroll
            for (int b = 0; b < B_BASES; ++b)
                acc[b] = make_float4(0.f, 0.f, 0.f, 0.f);
#pragma unroll
            for (int r = 0; r < R_REL; ++r) {
                int b0 = segbeg[key0 + r];
                int e0 = cursors[key0 + r];    // post-scatter == segment end
                int d = e0 - b0;
                float inv = 1.0f / (float)(d > 1 ? d : 1);
                float a0 = 0.f, a1 = 0.f, a2 = 0.f, a3 = 0.f;
                int i = b0;
                for (; i + 3 < e0; i += 4) {   // 4 uint2 loads in flight/half
                    int s0 = sorted[i], s1 = sorted[i + 1];
                    int s2 = sorted[i + 2], s3 = sorted[i + 3];
                    uint2 u0 = xb2[(size_t)s0 * 32 + hl];
                    uint2 u1 = xb2[(size_t)s1 * 32 + hl];
                    uint2 u2 = xb2[(size_t)s2 * 32 + hl];
                    uint2 u3 = xb2[(size_t)s3 * 32 + hl];
                    a0 += (__uint_as_float(u0.x << 16) + __uint_as_float(u1.x << 16))
                        + (__uint_as_float(u2.x << 16) + __uint_as_float(u3.x << 16));
                    a1 += (__uint_as_float(u0.x & 0xFFFF0000u) + __uint_as_float(u1.x & 0xFFFF0000u))
                        + (__uint_as_float(u2.x & 0xFFFF0000u) + __uint_as_float(u3.x & 0xFFFF0000u));
                    a2 += (__uint_as_float(u0.y << 16) + __uint_as_float(u1.y << 16))
                        + (__uint_as_float(u2.y << 16) + __uint_as_float(u3.y << 16));
                    a3 += (__uint_as_float(u0.y & 0xFFFF0000u) + __uint_as_float(u1.y & 0xFFFF0000u))
                        + (__uint_as_float(u2.y & 0xFFFF0000u) + __uint_as_float(u3.y & 0xFFFF0000u));
                }
                for (; i < e0; ++i) {
                    int s = sorted[i];
                    uint2 u = xb2[(size_t)s * 32 + hl];
                    a0 += __uint_as_float(u.x << 16);
                    a1 += __uint_as_float(u.x & 0xFFFF0000u);
                    a2 += __uint_as_float(u.y << 16);
                    a3 += __uint_as_float(u.y & 0xFFFF0000u);
                }
#pragma unroll
                for (int b = 0; b < B_BASES; ++b) {
                    float c = w_comp[r * B_BASES + b] * inv;
                    acc[b].x = fmaf(c, a0, acc[b].x);
                    acc[b].y = fmaf(c, a1, acc[b].y);
                    acc[b].z = fmaf(c, a2, acc[b].z);
                    acc[b].w = fmaf(c, a3, acc[b].w);
                }
            }
            if (node < N_NODES) {
                uint2* yrow = (uint2*)(y + (size_t)node * 256);   // [128] uint2
#pragma unroll
                for (int b = 0; b < B_BASES; ++b) {
                    __hip_bfloat162 h0 = __float22bfloat162_rn(make_float2(acc[b].x, acc[b].y));
                    __hip_bfloat162 h1 = __float22bfloat162_rn(make_float2(acc[b].z, acc[b].w));
                    uint2 v = make_uint2(*(uint*)&h0, *(uint*)&h1);
                    yrow[b * 32 + hl] = v;     // 256 B contiguous per half
                }
            }
        }
    } else {
        // fallback (fp32 x): original full-wave gather
        const float* xp = x + 2 * lane;
        for (int nn = 0; nn < 4; ++nn) {
            int nl = wid * 4 + nn;
            int node = bucket * 128 + sub * 32 + nl;
            int key0 = nl * 8;
            float2 acc[B_BASES];
#pragma unroll
            for (int b = 0; b < B_BASES; ++b) acc[b] = make_float2(0.f, 0.f);
#pragma unroll
            for (int r = 0; r < R_REL; ++r) {
                int b0 = segbeg[key0 + r];
                int e0 = cursors[key0 + r];
                int d = e0 - b0;
                float inv = 1.0f / (float)(d > 1 ? d : 1);
                float ax = 0.f, ay = 0.f;
                int i = b0;
                for (; i + 3 < e0; i += 4) {
                    int s0 = sorted[i], s1 = sorted[i + 1], s2 = sorted[i + 2], s3 = sorted[i + 3];
                    float2 a = *(const float2*)(xp + (size_t)s0 * D_FEAT);
                    float2 b = *(const float2*)(xp + (size_t)s1 * D_FEAT);
                    float2 cc = *(const float2*)(xp + (size_t)s2 * D_FEAT);
                    float2 d2 = *(const float2*)(xp + (size_t)s3 * D_FEAT);
                    ax += (a.x + b.x) + (cc.x + d2.x);
                    ay += (a.y + b.y) + (cc.y + d2.y);
                }
                for (; i < e0; ++i) {
                    int s = sorted[i];
                    float2 a = *(const float2*)(xp + (size_t)s * D_FEAT);
                    ax += a.x; ay += a.y;
                }
#pragma unroll
                for (int b = 0; b < B_BASES; ++b) {
                    float coef = w_comp[r * B_BASES + b] * inv;
                    acc[b].x = fmaf(coef, ax, acc[b].x);
                    acc[b].y = fmaf(coef, ay, acc[b].y);
                }
            }
            if (node < N_NODES) {
#pragma unroll
                for (int b = 0; b < B_BASES; ++b)
                    y[(size_t)node * 256 + b * 64 + lane] = __float22bfloat162_rn(acc[b]);
            }
        }
    }
}

// ---- fused MLP v2: M=32 rows/wave (each B-load feeds 2 MFMAs) ------------
// out = relu(relu(relu([y|x]@wT^T + bias) @ w0) @ w1). Block = 4 waves x 32
// rows = 128 rows. Intermediate activations in per-wave padded LDS tile
// (32 x 136 bf16) converting C-fragment layout -> A-fragment layout.
// Self-loop K-range reads xb (bf16) directly when available.
#define TPAD 136
template <bool XB>
__global__ __launch_bounds__(256) void fused_mlp(
    const short* __restrict__ y,            // [N][512] bf16
    const float* __restrict__ x,            // [N][128] fp32
    const uint*  __restrict__ xb,           // [N][64] bf162 pairs
    const unsigned short* __restrict__ wT,  // [128][640] bf16, n-major
    const float* __restrict__ bias,
    const unsigned short* __restrict__ wT2, // [2][128][128] bf16, n-major
    float* __restrict__ out) {              // [N][128] fp32
    __shared__ short tile[4][32][TPAD];     // 34.8 KB
    const int wave = threadIdx.x >> 6;
    const int lane = threadIdx.x & 63;
    const int quad = lane >> 4;
    const int l16  = lane & 15;
    const int rbase = blockIdx.x * 128 + wave * 32;
    int r0 = rbase + l16;      if (r0 >= N_NODES) r0 = N_NODES - 1;
    int r1 = rbase + 16 + l16; if (r1 >= N_NODES) r1 = N_NODES - 1;
    short (*tl)[TPAD] = tile[wave];
    const int koff = quad * 8;

    floatx4 acc0[8], acc1[8];
#pragma unroll
    for (int nt = 0; nt < 8; ++nt) {
        acc0[nt] = (floatx4){0.f, 0.f, 0.f, 0.f};
        acc1[nt] = (floatx4){0.f, 0.f, 0.f, 0.f};
    }

    // ---- layer 0: [y | x] @ wT^T, K=640; one B-load feeds both row-groups
    const short* y0 = y + (size_t)r0 * 512;
    const short* y1 = y + (size_t)r1 * 512;
    for (int ks = 0; ks < 16; ++ks) {
        int k0 = ks * 32 + koff;
        short8 a0 = *(const short8*)(y0 + k0);
        short8 a1 = *(const short8*)(y1 + k0);
#pragma unroll
        for (int nt = 0; nt < 8; ++nt) {
            int n = nt * 16 + l16;
            short8 b = *(const short8*)((const short*)wT + (size_t)n * 640 + k0);
            acc0[nt] = __builtin_amdgcn_mfma_f32_16x16x32_bf16(a0, b, acc0[nt], 0, 0, 0);
            acc1[nt] = __builtin_amdgcn_mfma_f32_16x16x32_bf16(a1, b, acc1[nt], 0, 0, 0);
        }
    }
    if (XB) {
        const short* xb0 = (const short*)xb + (size_t)r0 * 128;
        const short* xb1 = (const short*)xb + (size_t)r1 * 128;
#pragma unroll
        for (int ks = 0; ks < 4; ++ks) {
            int kl = ks * 32 + koff;
            short8 a0 = *(const short8*)(xb0 + kl);
            short8 a1 = *(const short8*)(xb1 + kl);
#pragma unroll
            for (int nt = 0; nt < 8; ++nt) {
                int n = nt * 16 + l16;
                short8 b = *(const short8*)((const short*)wT + (size_t)n * 640 + 512 + kl);
                acc0[nt] = __builtin_amdgcn_mfma_f32_16x16x32_bf16(a0, b, acc0[nt], 0, 0, 0);
                acc1[nt] = __builtin_amdgcn_mfma_f32_16x16x32_bf16(a1, b, acc1[nt], 0, 0, 0);
            }
        }
    } else {
        const float* x0 = x + (size_t)r0 * 128;
        const float* x1 = x + (size_t)r1 * 128;
#pragma unroll
        for (int ks = 0; ks < 4; ++ks) {
            int kl = ks * 32 + koff;
            union { short8 s; uint u[4]; } ua0, ua1;
            {
                float4 fa = *(const float4*)(x0 + kl);
                float4 fb = *(const float4*)(x0 + kl + 4);
                __hip_bfloat162 h0 = __float22bfloat162_rn(make_float2(fa.x, fa.y));
                __hip_bfloat162 h1 = __float22bfloat162_rn(make_float2(fa.z, fa.w));
                __hip_bfloat162 h2 = __float22bfloat162_rn(make_float2(fb.x, fb.y));
                __hip_bfloat162 h3 = __float22bfloat162_rn(make_float2(fb.z, fb.w));
                ua0.u[0] = *(uint*)&h0; ua0.u[1] = *(uint*)&h1;
                ua0.u[2] = *(uint*)&h2; ua0.u[3] = *(uint*)&h3;
            }
            {
                float4 fa = *(const float4*)(x1 + kl);
                float4 fb = *(const float4*)(x1 + kl + 4);
                __hip_bfloat162 h0 = __float22bfloat162_rn(make_float2(fa.x, fa.y));
                __hip_bfloat162 h1 = __float22bfloat162_rn(make_float2(fa.z, fa.w));
                __hip_bfloat162 h2 = __float22bfloat162_rn(make_float2(fb.x, fb.y));
                __hip_bfloat162 h3 = __float22bfloat162_rn(make_float2(fb.z, fb.w));
                ua1.u[0] = *(uint*)&h0; ua1.u[1] = *(uint*)&h1;
                ua1.u[2] = *(uint*)&h2; ua1.u[3] = *(uint*)&h3;
            }
#pragma unroll
            for (int nt = 0; nt < 8; ++nt) {
                int n = nt * 16 + l16;
                short8 b = *(const short8*)((const short*)wT + (size_t)n * 640 + 512 + kl);
                acc0[nt] = __builtin_amdgcn_mfma_f32_16x16x32_bf16(ua0.s, b, acc0[nt], 0, 0, 0);
                acc1[nt] = __builtin_amdgcn_mfma_f32_16x16x32_bf16(ua1.s, b, acc1[nt], 0, 0, 0);
            }
        }
    }

    // relu(+bias) -> LDS tile (C-layout write; tile is wave-local)
#pragma unroll
    for (int nt = 0; nt < 8; ++nt) {
        float bs = bias[nt * 16 + l16];
#pragma unroll
        for (int i = 0; i < 4; ++i) {
            int row = quad * 4 + i;
            float v0 = fmaxf(acc0[nt][i] + bs, 0.f);
            float v1 = fmaxf(acc1[nt][i] + bs, 0.f);
            __hip_bfloat16 h0 = __float2bfloat16(v0);
            __hip_bfloat16 h1 = __float2bfloat16(v1);
            tl[row][nt * 16 + l16]      = *(short*)&h0;
            tl[16 + row][nt * 16 + l16] = *(short*)&h1;
        }
    }
    __syncthreads();

    // ---- NGNN layers: K=128 each, A from LDS tile ----
#pragma unroll
    for (int l = 0; l < 2; ++l) {
        const unsigned short* wl = wT2 + l * 16384;
        short8 af0[4], af1[4];
#pragma unroll
        for (int ks = 0; ks < 4; ++ks) {
            af0[ks] = *(const short8*)&tl[l16][ks * 32 + koff];
            af1[ks] = *(const short8*)&tl[16 + l16][ks * 32 + koff];
        }
        floatx4 ac0[8], ac1[8];
#pragma unroll
        for (int nt = 0; nt < 8; ++nt) {
            ac0[nt] = (floatx4){0.f, 0.f, 0.f, 0.f};
            ac1[nt] = (floatx4){0.f, 0.f, 0.f, 0.f};
        }
#pragma unroll
        for (int ks = 0; ks < 4; ++ks) {
            int k0 = ks * 32 + koff;
#pragma unroll
            for (int nt = 0; nt < 8; ++nt) {
                int n = nt * 16 + l16;
                short8 b = *(const short8*)((const short*)wl + (size_t)n * 128 + k0);
                ac0[nt] = __builtin_amdgcn_mfma_f32_16x16x32_bf16(af0[ks], b, ac0[nt], 0, 0, 0);
                ac1[nt] = __builtin_amdgcn_mfma_f32_16x16x32_bf16(af1[ks], b, ac1[nt], 0, 0, 0);
            }
        }
        if (l == 0) {
            __syncthreads();   // all af reads done before overwrite
#pragma unroll
            for (int nt = 0; nt < 8; ++nt)
#pragma unroll
                for (int i = 0; i < 4; ++i) {
                    int row = quad * 4 + i;
                    float v0 = fmaxf(ac0[nt][i], 0.f);
                    float v1 = fmaxf(ac1[nt][i], 0.f);
                    __hip_bfloat16 h0 = __float2bfloat16(v0);
                    __hip_bfloat16 h1 = __float2bfloat16(v1);
                    tl[row][nt * 16 + l16]      = *(short*)&h0;
                    tl[16 + row][nt * 16 + l16] = *(short*)&h1;
                }
            __syncthreads();
        } else {
#pragma unroll
            for (int nt = 0; nt < 8; ++nt) {
                int n = nt * 16 + l16;
#pragma unroll
                for (int i = 0; i < 4; ++i) {
                    int m0 = rbase + quad * 4 + i;
                    int m1 = rbase + 16 + quad * 4 + i;
                    if (m0 < N_NODES)
                        out[(size_t)m0 * D_FEAT + n] = fmaxf(ac0[nt][i], 0.f);
                    if (m1 < N_NODES)
                        out[(size_t)m1 * D_FEAT + n] = fmaxf(ac1[nt][i], 0.f);
                }
            }
        }
    }
}

extern "C" void kernel_launch(void* const* d_in, const int* in_sizes, int n_in,
                              void* d_out, int out_size, void* d_ws, size_t ws_size,
                              hipStream_t stream) {
    const float* x           = (const float*)d_in[0];
    const int*   edge_src    = (const int*)d_in[1];
    const int*   edge_dst    = (const int*)d_in[2];
    const float* w_comp      = (const float*)d_in[3];
    const float* bases       = (const float*)d_in[4];
    const float* loop_weight = (const float*)d_in[5];
    const float* h_bias      = (const float*)d_in[6];
    const float* ngnn_w      = (const float*)d_in[7];
    float* out = (float*)d_out;

    // workspace layout (~131.6 MB base; +25.6 MB optional xb)
    char* ws = (char*)d_ws;
    size_t off = 0;
    __hip_bfloat162* y = (__hip_bfloat162*)(ws + off);
    off += (size_t)N_NODES * 512 * 2;              // 102.4 MB
    int* ebuf2 = (int*)(ws + off);                 // 784*9216*4 = 28.9 MB
    off += (size_t)NBKT * BKT_CAP * 4;
    int* gcursor = (int*)(ws + off);
    off += 4096;
    unsigned short* wT = (unsigned short*)(ws + off);
    off += (size_t)128 * 640 * 2;                  // 160 KB
    unsigned short* wT2 = (unsigned short*)(ws + off);
    off += (size_t)2 * 128 * 128 * 2;              // 64 KB
    uint* xb = (uint*)(ws + off);
    size_t xb_bytes = (size_t)N_NODES * 64 * 4;    // 25.6 MB
    const bool use_bf16_x = (ws_size >= off + xb_bytes);   // ws_size constant across calls

    // 0) fused prep: xcvt + wcvt + wcvt2 + cursor init (one launch)
    int prep_items = (use_bf16_x ? NXW : 0) + NW1 + NW2 + NBKT;
    prep_kernel<<<(prep_items + 255) / 256, 256, 0, stream>>>(
        x, xb, bases, loop_weight, wT, ngnn_w, wT2, gcursor, use_bf16_x ? 1 : 0);

    // 1) bucket partition
    p1_kernel<<<P1_NWG, P1_TPB, 0, stream>>>(edge_src, edge_dst, gcursor, ebuf2);

    // 2) fused filter + LDS-sort + gather -> y (bf16, basis-combined, deg-normalized)
    if (use_bf16_x)
        agg3_kernel<true><<<SGRID, 512, 0, stream>>>(x, xb, gcursor, ebuf2, w_comp, y);
    else
        agg3_kernel<false><<<SGRID, 512, 0, stream>>>(x, nullptr, gcursor, ebuf2, w_comp, y);

    // 3) fused MLP: gemm_big + ngnn0 + ngnn1, M=32 rows/wave
    const int MLP_GRID = (N_NODES + 127) / 128;    // 782
    if (use_bf16_x)
        fused_mlp<true><<<MLP_GRID, 256, 0, stream>>>(
            (const short*)y, x, xb, wT, h_bias, wT2, out);
    else
        fused_mlp<false><<<MLP_GRID, 256, 0, stream>>>(
            (const short*)y, x, nullptr, wT, h_bias, wT2, out);
}

// Round 9
// 588.321 us; speedup vs baseline: 1.0283x; 1.0283x over previous
//
#include <hip/hip_runtime.h>
#include <hip/hip_bf16.h>

#define N_NODES 100000
#define R_REL   8
#define E_EDGES 800000
#define D_FEAT  128
#define B_BASES 4
#define RN      (R_REL * N_NODES)
#define RE      (R_REL * E_EDGES)          // 6.4M edges

// radix partition: 784 coarse buckets of 128 dst nodes each
#define NBKT    784
#define BKT_CAP 9216                       // mean 8163, +11 sigma slack
#define P1_TPB  256
#define P1_EPT  32
#define P1_CHUNK (P1_TPB * P1_EPT)         // 8192 edges / WG
#define P1_NWG  ((RE + P1_CHUNK - 1) / P1_CHUNK)   // 782

// agg: 4 sub-buckets of 32 dst nodes per coarse bucket
#define SUB_PER_BKT 4
#define SGRID   (NBKT * SUB_PER_BKT)       // 3136
#define SUBCAP  2816                       // mean 2041, +17 sigma slack

#define NXW  (N_NODES * 64)                // xcvt items
#define NW1  (128 * 640)                   // wcvt items
#define NW2  (2 * 128 * 128)               // wcvt2 items

typedef __attribute__((ext_vector_type(8))) short short8;
typedef __attribute__((ext_vector_type(4))) float floatx4;

// ---- fused prep: xcvt + wcvt + wcvt2 + cursor init in ONE launch ----------
__global__ __launch_bounds__(256) void prep_kernel(
    const float* __restrict__ x, uint* __restrict__ xb,
    const float* __restrict__ bases, const float* __restrict__ loopw,
    unsigned short* __restrict__ wT,
    const float* __restrict__ ngnn_w, unsigned short* __restrict__ wT2,
    int* __restrict__ gcursor, int do_x) {
    int idx = blockIdx.x * 256 + threadIdx.x;
    if (do_x) {
        if (idx < NXW) {                       // x (fp32) -> xb (bf162 pairs)
            float2 v = *(const float2*)(x + 2 * (size_t)idx);
            __hip_bfloat162 h = __float22bfloat162_rn(v);
            xb[idx] = *(uint*)&h;
            return;
        }
        idx -= NXW;
    }
    if (idx < NW1) {                           // wT[n][k]
        int n = idx / 640, k = idx % 640;
        float v = (k < 512) ? bases[(size_t)k * 128 + n]
                            : loopw[(size_t)(k - 512) * 128 + n];
        __hip_bfloat16 h = __float2bfloat16(v);
        wT[idx] = *(unsigned short*)&h;
        return;
    }
    idx -= NW1;
    if (idx < NW2) {                           // wT2[l][n][k]
        int l = idx >> 14, rem = idx & 16383;
        int n = rem >> 7, k = rem & 127;
        float v = ngnn_w[(size_t)l * 16384 + (size_t)k * 128 + n];
        __hip_bfloat16 h = __float2bfloat16(v);
        wT2[idx] = *(unsigned short*)&h;
        return;
    }
    idx -= NW2;
    if (idx < NBKT) gcursor[idx] = idx * BKT_CAP;
}

// ---- pass 1: partition edges into coarse dst-buckets (coalesced writes) ---
// record = src(17b) | dst_low(7b)<<17 | r(3b)<<24
__global__ __launch_bounds__(256) void p1_kernel(
    const int* __restrict__ src, const int* __restrict__ dst,
    int* __restrict__ gcursor, int* __restrict__ ebuf2) {
    __shared__ int hist[NBKT];
    __shared__ int cnt2[NBKT];
    __shared__ int basebkt[NBKT];
    __shared__ int lofs[NBKT];
    __shared__ int aux[256];
    __shared__ int recs[P1_CHUNK];           // 32 KB
    __shared__ unsigned short bb[P1_CHUNK];  // 16 KB
    int t = threadIdx.x;
    for (int i = t; i < NBKT; i += 256) { hist[i] = 0; cnt2[i] = 0; }
    __syncthreads();

    int e0 = blockIdx.x * P1_CHUNK;
    int rec[P1_EPT];
    int bkt[P1_EPT];
#pragma unroll
    for (int i = 0; i < P1_EPT; ++i) {
        int e = e0 + i * P1_TPB + t;         // coalesced
        if (e < RE) {
            int d = dst[e];
            int s = src[e];
            int r = e / E_EDGES;             // magic-mul division
            bkt[i] = d >> 7;
            rec[i] = s | ((d & 127) << 17) | (r << 24);
            atomicAdd(&hist[bkt[i]], 1);     // native int ds_add
        } else bkt[i] = -1;
    }
    __syncthreads();

    // exclusive scan of hist[784]: 4 consecutive per thread + Hillis-Steele
    int k0 = t * 4;
    int c0 = (k0 + 0 < NBKT) ? hist[k0 + 0] : 0;
    int c1 = (k0 + 1 < NBKT) ? hist[k0 + 1] : 0;
    int c2 = (k0 + 2 < NBKT) ? hist[k0 + 2] : 0;
    int c3 = (k0 + 3 < NBKT) ? hist[k0 + 3] : 0;
    int s1 = c0 + c1, s2 = s1 + c2, s3 = s2 + c3;
    aux[t] = s3;
    __syncthreads();
    int vv = s3;
    for (int off = 1; off < 256; off <<= 1) {
        int yv = (t >= off) ? aux[t - off] : 0;
        __syncthreads();
        vv += yv;
        aux[t] = vv;
        __syncthreads();
    }
    int total = aux[255];
    int texcl = vv - s3;
    if (k0 + 0 < NBKT) lofs[k0 + 0] = texcl;
    if (k0 + 1 < NBKT) lofs[k0 + 1] = texcl + c0;
    if (k0 + 2 < NBKT) lofs[k0 + 2] = texcl + s1;
    if (k0 + 3 < NBKT) lofs[k0 + 3] = texcl + s2;
    __syncthreads();
    for (int i = t; i < NBKT; i += 256) {
        int hv = hist[i];
        basebkt[i] = (hv > 0) ? atomicAdd(&gcursor[i], hv) : 0;
    }
    __syncthreads();

    // reorder records into bucket-contiguous LDS slots
#pragma unroll
    for (int i = 0; i < P1_EPT; ++i) {
        if (bkt[i] >= 0) {
            int p = lofs[bkt[i]] + atomicAdd(&cnt2[bkt[i]], 1);
            recs[p] = rec[i];
            bb[p] = (unsigned short)bkt[i];
        }
    }
    __syncthreads();

    // writeout: consecutive i are mostly same-bucket runs
    for (int i = t; i < total; i += 256) {
        int b = bb[i];
        int p2 = basebkt[b] + (i - lofs[b]);
        if (p2 < (b + 1) * BKT_CAP) ebuf2[p2] = recs[i];
    }
}

// ---- fused sort+gather (R7 structure, proven 268 us; + 8-deep unroll) ----
// 512 thr (8 waves), 4 WGs/CU (~25 KB LDS). id = sub*784 + bucket: the 4
// sub-WGs of one bucket are congruent mod 8 (784 % 8 == 0) -> same XCD
// under round-robin dispatch, so the 4x coarse-bucket re-read hits one L2.
// Gather: full-wave ownership of one node (wave-uniform control flow —
// sub-wave splits diverge, R8), per-lane 4B loads, 8 loads in flight for
// segments >= 8 (mean segment = 8), store lane-linear full-line.
template <bool XB>
__global__ __launch_bounds__(512, 8) void agg3_kernel(
    const float* __restrict__ x,
    const uint*  __restrict__ xb,          // [N][64] bf162 pairs
    const int*   __restrict__ gcursor,
    const int*   __restrict__ ebuf2,
    const float* __restrict__ w_comp,
    __hip_bfloat162* __restrict__ y) {     // [N][256] bf162
    __shared__ int raw[SUBCAP];            // 11 KB
    __shared__ int sorted[SUBCAP];         // 11 KB (head doubles as scan aux)
    __shared__ int cursors[256];
    __shared__ int segbeg[256];
    __shared__ int nraw;
    const int t = threadIdx.x;
    const int bucket = blockIdx.x % NBKT;  // co-XCD mapping for the 4 sub-WGs
    const int sub    = blockIdx.x / NBKT;

    int cnt = gcursor[bucket] - bucket * BKT_CAP;
    if (cnt > BKT_CAP) cnt = BKT_CAP;
    const int* brec = ebuf2 + (size_t)bucket * BKT_CAP;
    if (t < 256) cursors[t] = 0;
    if (t == 0) nraw = 0;
    __syncthreads();

    const int lane = t & 63;
    const unsigned long long lmask = (1ull << lane) - 1ull;

    // single global pass: compact matching records into raw[] + histogram
    for (int i0 = 0; i0 < cnt; i0 += 512) {
        int i = i0 + t;
        int rec = (i < cnt) ? brec[i] : 0;
        bool match = (i < cnt) && ((((rec >> 17) & 127) >> 5) == sub);
        unsigned long long mask = __ballot(match);
        int base = 0;
        if (lane == 0) base = atomicAdd(&nraw, (int)__popcll(mask));
        base = __shfl(base, 0);
        if (match) {
            int p = base + (int)__popcll(mask & lmask);
            if (p < SUBCAP) {
                raw[p] = rec;
                int key = ((rec >> 17) & 31) * 8 + ((rec >> 24) & 7);
                atomicAdd(&cursors[key], 1);
            }
        }
    }
    __syncthreads();
    int n = nraw; if (n > SUBCAP) n = SUBCAP;

    // exclusive scan of 256 degrees (aux aliases sorted[0..511])
    int deg = (t < 256) ? cursors[t] : 0;
    int* aux = sorted;
    aux[t] = deg;
    __syncthreads();
    int vv = deg;
    for (int off = 1; off < 256; off <<= 1) {
        int yv = (t >= off && t < 256) ? aux[t - off] : 0;
        __syncthreads();
        vv += yv;
        aux[t] = vv;
        __syncthreads();
    }
    if (t < 256) {
        cursors[t] = vv - deg;
        segbeg[t]  = vv - deg;
    }
    __syncthreads();

    // in-LDS scatter to sorted order (src ids only)
    for (int i = t; i < n; i += 512) {
        int rec = raw[i];
        int key = ((rec >> 17) & 31) * 8 + ((rec >> 24) & 7);
        int pos = atomicAdd(&cursors[key], 1);   // ds_add_rtn_u32
        sorted[pos] = rec & 0x1FFFF;
    }
    __syncthreads();

    // gather: wave owns 4 nodes; per (node,r) segment sum then basis fold
    const int wid = t >> 6;
    const float* xp  = x + 2 * lane;
    const uint*  xbp = xb + lane;
    for (int nn = 0; nn < 4; ++nn) {
        int nl = wid * 4 + nn;                   // 0..31 within sub-bucket
        int node = bucket * 128 + sub * 32 + nl;
        int key0 = nl * 8;
        float2 acc[B_BASES];
#pragma unroll
        for (int b = 0; b < B_BASES; ++b) acc[b] = make_float2(0.f, 0.f);
#pragma unroll
        for (int r = 0; r < R_REL; ++r) {
            int b0 = segbeg[key0 + r];
            int e0 = cursors[key0 + r];      // post-scatter == segment end
            int d = e0 - b0;
            float inv = 1.0f / (float)(d > 1 ? d : 1);
            float ax = 0.f, ay = 0.f;
            int i = b0;
            if (XB) {
                for (; i + 7 < e0; i += 8) {     // 8 loads in flight
                    int s0 = sorted[i],     s1 = sorted[i + 1];
                    int s2 = sorted[i + 2], s3 = sorted[i + 3];
                    int s4 = sorted[i + 4], s5 = sorted[i + 5];
                    int s6 = sorted[i + 6], s7 = sorted[i + 7];
                    uint u0 = xbp[(size_t)s0 * 64];
                    uint u1 = xbp[(size_t)s1 * 64];
                    uint u2 = xbp[(size_t)s2 * 64];
                    uint u3 = xbp[(size_t)s3 * 64];
                    uint u4 = xbp[(size_t)s4 * 64];
                    uint u5 = xbp[(size_t)s5 * 64];
                    uint u6 = xbp[(size_t)s6 * 64];
                    uint u7 = xbp[(size_t)s7 * 64];
                    ax += ((__uint_as_float(u0 << 16) + __uint_as_float(u1 << 16))
                         + (__uint_as_float(u2 << 16) + __uint_as_float(u3 << 16)))
                        + ((__uint_as_float(u4 << 16) + __uint_as_float(u5 << 16))
                         + (__uint_as_float(u6 << 16) + __uint_as_float(u7 << 16)));
                    ay += ((__uint_as_float(u0 & 0xFFFF0000u) + __uint_as_float(u1 & 0xFFFF0000u))
                         + (__uint_as_float(u2 & 0xFFFF0000u) + __uint_as_float(u3 & 0xFFFF0000u)))
                        + ((__uint_as_float(u4 & 0xFFFF0000u) + __uint_as_float(u5 & 0xFFFF0000u))
                         + (__uint_as_float(u6 & 0xFFFF0000u) + __uint_as_float(u7 & 0xFFFF0000u)));
                }
            }
            for (; i + 3 < e0; i += 4) {
                int s0 = sorted[i], s1 = sorted[i + 1], s2 = sorted[i + 2], s3 = sorted[i + 3];
                if (XB) {
                    uint u0 = xbp[(size_t)s0 * 64];
                    uint u1 = xbp[(size_t)s1 * 64];
                    uint u2 = xbp[(size_t)s2 * 64];
                    uint u3 = xbp[(size_t)s3 * 64];
                    ax += (__uint_as_float(u0 << 16) + __uint_as_float(u1 << 16))
                        + (__uint_as_float(u2 << 16) + __uint_as_float(u3 << 16));
                    ay += (__uint_as_float(u0 & 0xFFFF0000u) + __uint_as_float(u1 & 0xFFFF0000u))
                        + (__uint_as_float(u2 & 0xFFFF0000u) + __uint_as_float(u3 & 0xFFFF0000u));
                } else {
                    float2 a = *(const float2*)(xp + (size_t)s0 * D_FEAT);
                    float2 b = *(const float2*)(xp + (size_t)s1 * D_FEAT);
                    float2 cc = *(const float2*)(xp + (size_t)s2 * D_FEAT);
                    float2 d2 = *(const float2*)(xp + (size_t)s3 * D_FEAT);
                    ax += (a.x + b.x) + (cc.x + d2.x);
                    ay += (a.y + b.y) + (cc.y + d2.y);
                }
            }
            for (; i < e0; ++i) {
                int s = sorted[i];
                if (XB) {
                    uint u = xbp[(size_t)s * 64];
                    ax += __uint_as_float(u << 16);
                    ay += __uint_as_float(u & 0xFFFF0000u);
                } else {
                    float2 a = *(const float2*)(xp + (size_t)s * D_FEAT);
                    ax += a.x; ay += a.y;
                }
            }
#pragma unroll
            for (int b = 0; b < B_BASES; ++b) {
                float coef = w_comp[r * B_BASES + b] * inv;
                acc[b].x = fmaf(coef, ax, acc[b].x);
                acc[b].y = fmaf(coef, ay, acc[b].y);
            }
        }
        if (node < N_NODES) {
#pragma unroll
            for (int b = 0; b < B_BASES; ++b)
                y[(size_t)node * 256 + b * 64 + lane] = __float22bfloat162_rn(acc[b]);
        }
    }
}

// ---- fused MLP v2: M=32 rows/wave (each B-load feeds 2 MFMAs) ------------
// out = relu(relu(relu([y|x]@wT^T + bias) @ w0) @ w1). Block = 4 waves x 32
// rows = 128 rows. Intermediate activations in per-wave padded LDS tile
// (32 x 136 bf16) converting C-fragment layout -> A-fragment layout.
// Self-loop K-range reads xb (bf16) directly when available.
#define TPAD 136
template <bool XB>
__global__ __launch_bounds__(256) void fused_mlp(
    const short* __restrict__ y,            // [N][512] bf16
    const float* __restrict__ x,            // [N][128] fp32
    const uint*  __restrict__ xb,           // [N][64] bf162 pairs
    const unsigned short* __restrict__ wT,  // [128][640] bf16, n-major
    const float* __restrict__ bias,
    const unsigned short* __restrict__ wT2, // [2][128][128] bf16, n-major
    float* __restrict__ out) {              // [N][128] fp32
    __shared__ short tile[4][32][TPAD];     // 34.8 KB
    const int wave = threadIdx.x >> 6;
    const int lane = threadIdx.x & 63;
    const int quad = lane >> 4;
    const int l16  = lane & 15;
    const int rbase = blockIdx.x * 128 + wave * 32;
    int r0 = rbase + l16;      if (r0 >= N_NODES) r0 = N_NODES - 1;
    int r1 = rbase + 16 + l16; if (r1 >= N_NODES) r1 = N_NODES - 1;
    short (*tl)[TPAD] = tile[wave];
    const int koff = quad * 8;

    floatx4 acc0[8], acc1[8];
#pragma unroll
    for (int nt = 0; nt < 8; ++nt) {
        acc0[nt] = (floatx4){0.f, 0.f, 0.f, 0.f};
        acc1[nt] = (floatx4){0.f, 0.f, 0.f, 0.f};
    }

    // ---- layer 0: [y | x] @ wT^T, K=640; one B-load feeds both row-groups
    const short* y0 = y + (size_t)r0 * 512;
    const short* y1 = y + (size_t)r1 * 512;
    for (int ks = 0; ks < 16; ++ks) {
        int k0 = ks * 32 + koff;
        short8 a0 = *(const short8*)(y0 + k0);
        short8 a1 = *(const short8*)(y1 + k0);
#pragma unroll
        for (int nt = 0; nt < 8; ++nt) {
            int n = nt * 16 + l16;
            short8 b = *(const short8*)((const short*)wT + (size_t)n * 640 + k0);
            acc0[nt] = __builtin_amdgcn_mfma_f32_16x16x32_bf16(a0, b, acc0[nt], 0, 0, 0);
            acc1[nt] = __builtin_amdgcn_mfma_f32_16x16x32_bf16(a1, b, acc1[nt], 0, 0, 0);
        }
    }
    if (XB) {
        const short* xb0 = (const short*)xb + (size_t)r0 * 128;
        const short* xb1 = (const short*)xb + (size_t)r1 * 128;
#pragma unroll
        for (int ks = 0; ks < 4; ++ks) {
            int kl = ks * 32 + koff;
            short8 a0 = *(const short8*)(xb0 + kl);
            short8 a1 = *(const short8*)(xb1 + kl);
#pragma unroll
            for (int nt = 0; nt < 8; ++nt) {
                int n = nt * 16 + l16;
                short8 b = *(const short8*)((const short*)wT + (size_t)n * 640 + 512 + kl);
                acc0[nt] = __builtin_amdgcn_mfma_f32_16x16x32_bf16(a0, b, acc0[nt], 0, 0, 0);
                acc1[nt] = __builtin_amdgcn_mfma_f32_16x16x32_bf16(a1, b, acc1[nt], 0, 0, 0);
            }
        }
    } else {
        const float* x0 = x + (size_t)r0 * 128;
        const float* x1 = x + (size_t)r1 * 128;
#pragma unroll
        for (int ks = 0; ks < 4; ++ks) {
            int kl = ks * 32 + koff;
            union { short8 s; uint u[4]; } ua0, ua1;
            {
                float4 fa = *(const float4*)(x0 + kl);
                float4 fb = *(const float4*)(x0 + kl + 4);
                __hip_bfloat162 h0 = __float22bfloat162_rn(make_float2(fa.x, fa.y));
                __hip_bfloat162 h1 = __float22bfloat162_rn(make_float2(fa.z, fa.w));
                __hip_bfloat162 h2 = __float22bfloat162_rn(make_float2(fb.x, fb.y));
                __hip_bfloat162 h3 = __float22bfloat162_rn(make_float2(fb.z, fb.w));
                ua0.u[0] = *(uint*)&h0; ua0.u[1] = *(uint*)&h1;
                ua0.u[2] = *(uint*)&h2; ua0.u[3] = *(uint*)&h3;
            }
            {
                float4 fa = *(const float4*)(x1 + kl);
                float4 fb = *(const float4*)(x1 + kl + 4);
                __hip_bfloat162 h0 = __float22bfloat162_rn(make_float2(fa.x, fa.y));
                __hip_bfloat162 h1 = __float22bfloat162_rn(make_float2(fa.z, fa.w));
                __hip_bfloat162 h2 = __float22bfloat162_rn(make_float2(fb.x, fb.y));
                __hip_bfloat162 h3 = __float22bfloat162_rn(make_float2(fb.z, fb.w));
                ua1.u[0] = *(uint*)&h0; ua1.u[1] = *(uint*)&h1;
                ua1.u[2] = *(uint*)&h2; ua1.u[3] = *(uint*)&h3;
            }
#pragma unroll
            for (int nt = 0; nt < 8; ++nt) {
                int n = nt * 16 + l16;
                short8 b = *(const short8*)((const short*)wT + (size_t)n * 640 + 512 + kl);
                acc0[nt] = __builtin_amdgcn_mfma_f32_16x16x32_bf16(ua0.s, b, acc0[nt], 0, 0, 0);
                acc1[nt] = __builtin_amdgcn_mfma_f32_16x16x32_bf16(ua1.s, b, acc1[nt], 0, 0, 0);
            }
        }
    }

    // relu(+bias) -> LDS tile (C-layout write; tile is wave-local)
#pragma unroll
    for (int nt = 0; nt < 8; ++nt) {
        float bs = bias[nt * 16 + l16];
#pragma unroll
        for (int i = 0; i < 4; ++i) {
            int row = quad * 4 + i;
            float v0 = fmaxf(acc0[nt][i] + bs, 0.f);
            float v1 = fmaxf(acc1[nt][i] + bs, 0.f);
            __hip_bfloat16 h0 = __float2bfloat16(v0);
            __hip_bfloat16 h1 = __float2bfloat16(v1);
            tl[row][nt * 16 + l16]      = *(short*)&h0;
            tl[16 + row][nt * 16 + l16] = *(short*)&h1;
        }
    }
    __syncthreads();

    // ---- NGNN layers: K=128 each, A from LDS tile ----
#pragma unroll
    for (int l = 0; l < 2; ++l) {
        const unsigned short* wl = wT2 + l * 16384;
        short8 af0[4], af1[4];
#pragma unroll
        for (int ks = 0; ks < 4; ++ks) {
            af0[ks] = *(const short8*)&tl[l16][ks * 32 + koff];
            af1[ks] = *(const short8*)&tl[16 + l16][ks * 32 + koff];
        }
        floatx4 ac0[8], ac1[8];
#pragma unroll
        for (int nt = 0; nt < 8; ++nt) {
            ac0[nt] = (floatx4){0.f, 0.f, 0.f, 0.f};
            ac1[nt] = (floatx4){0.f, 0.f, 0.f, 0.f};
        }
#pragma unroll
        for (int ks = 0; ks < 4; ++ks) {
            int k0 = ks * 32 + koff;
#pragma unroll
            for (int nt = 0; nt < 8; ++nt) {
                int n = nt * 16 + l16;
                short8 b = *(const short8*)((const short*)wl + (size_t)n * 128 + k0);
                ac0[nt] = __builtin_amdgcn_mfma_f32_16x16x32_bf16(af0[ks], b, ac0[nt], 0, 0, 0);
                ac1[nt] = __builtin_amdgcn_mfma_f32_16x16x32_bf16(af1[ks], b, ac1[nt], 0, 0, 0);
            }
        }
        if (l == 0) {
            __syncthreads();   // all af reads done before overwrite
#pragma unroll
            for (int nt = 0; nt < 8; ++nt)
#pragma unroll
                for (int i = 0; i < 4; ++i) {
                    int row = quad * 4 + i;
                    float v0 = fmaxf(ac0[nt][i], 0.f);
                    float v1 = fmaxf(ac1[nt][i], 0.f);
                    __hip_bfloat16 h0 = __float2bfloat16(v0);
                    __hip_bfloat16 h1 = __float2bfloat16(v1);
                    tl[row][nt * 16 + l16]      = *(short*)&h0;
                    tl[16 + row][nt * 16 + l16] = *(short*)&h1;
                }
            __syncthreads();
        } else {
#pragma unroll
            for (int nt = 0; nt < 8; ++nt) {
                int n = nt * 16 + l16;
#pragma unroll
                for (int i = 0; i < 4; ++i) {
                    int m0 = rbase + quad * 4 + i;
                    int m1 = rbase + 16 + quad * 4 + i;
                    if (m0 < N_NODES)
                        out[(size_t)m0 * D_FEAT + n] = fmaxf(ac0[nt][i], 0.f);
                    if (m1 < N_NODES)
                        out[(size_t)m1 * D_FEAT + n] = fmaxf(ac1[nt][i], 0.f);
                }
            }
        }
    }
}

extern "C" void kernel_launch(void* const* d_in, const int* in_sizes, int n_in,
                              void* d_out, int out_size, void* d_ws, size_t ws_size,
                              hipStream_t stream) {
    const float* x           = (const float*)d_in[0];
    const int*   edge_src    = (const int*)d_in[1];
    const int*   edge_dst    = (const int*)d_in[2];
    const float* w_comp      = (const float*)d_in[3];
    const float* bases       = (const float*)d_in[4];
    const float* loop_weight = (const float*)d_in[5];
    const float* h_bias      = (const float*)d_in[6];
    const float* ngnn_w      = (const float*)d_in[7];
    float* out = (float*)d_out;

    // workspace layout (~131.6 MB base; +25.6 MB optional xb)
    char* ws = (char*)d_ws;
    size_t off = 0;
    __hip_bfloat162* y = (__hip_bfloat162*)(ws + off);
    off += (size_t)N_NODES * 512 * 2;              // 102.4 MB
    int* ebuf2 = (int*)(ws + off);                 // 784*9216*4 = 28.9 MB
    off += (size_t)NBKT * BKT_CAP * 4;
    int* gcursor = (int*)(ws + off);
    off += 4096;
    unsigned short* wT = (unsigned short*)(ws + off);
    off += (size_t)128 * 640 * 2;                  // 160 KB
    unsigned short* wT2 = (unsigned short*)(ws + off);
    off += (size_t)2 * 128 * 128 * 2;              // 64 KB
    uint* xb = (uint*)(ws + off);
    size_t xb_bytes = (size_t)N_NODES * 64 * 4;    // 25.6 MB
    const bool use_bf16_x = (ws_size >= off + xb_bytes);   // ws_size constant across calls

    // 0) fused prep: xcvt + wcvt + wcvt2 + cursor init (one launch)
    int prep_items = (use_bf16_x ? NXW : 0) + NW1 + NW2 + NBKT;
    prep_kernel<<<(prep_items + 255) / 256, 256, 0, stream>>>(
        x, xb, bases, loop_weight, wT, ngnn_w, wT2, gcursor, use_bf16_x ? 1 : 0);

    // 1) bucket partition
    p1_kernel<<<P1_NWG, P1_TPB, 0, stream>>>(edge_src, edge_dst, gcursor, ebuf2);

    // 2) fused filter + LDS-sort + gather -> y (bf16, basis-combined, deg-normalized)
    if (use_bf16_x)
        agg3_kernel<true><<<SGRID, 512, 0, stream>>>(x, xb, gcursor, ebuf2, w_comp, y);
    else
        agg3_kernel<false><<<SGRID, 512, 0, stream>>>(x, nullptr, gcursor, ebuf2, w_comp, y);

    // 3) fused MLP: gemm_big + ngnn0 + ngnn1, M=32 rows/wave
    const int MLP_GRID = (N_NODES + 127) / 128;    // 782
    if (use_bf16_x)
        fused_mlp<true><<<MLP_GRID, 256, 0, stream>>>(
            (const short*)y, x, xb, wT, h_bias, wT2, out);
    else
        fused_mlp<false><<<MLP_GRID, 256, 0, stream>>>(
            (const short*)y, x, nullptr, wT, h_bias, wT2, out);
}

// Round 10
// 579.250 us; speedup vs baseline: 1.0444x; 1.0157x over previous
//
#include <hip/hip_runtime.h>
#include <hip/hip_bf16.h>

#define N_NODES 100000
#define R_REL   8
#define E_EDGES 800000
#define D_FEAT  128
#define B_BASES 4
#define RN      (R_REL * N_NODES)
#define RE      (R_REL * E_EDGES)          // 6.4M edges

// radix partition: 784 coarse buckets of 128 dst nodes each
#define NBKT    784
#define BKT_CAP 9216                       // mean 8163, +11 sigma slack
#define P1_TPB  256
#define P1_EPT  32
#define P1_CHUNK (P1_TPB * P1_EPT)         // 8192 edges / WG
#define P1_NWG  ((RE + P1_CHUNK - 1) / P1_CHUNK)   // 782

// agg: 4 sub-buckets of 32 dst nodes per coarse bucket
#define SUB_PER_BKT 4
#define SGRID   (NBKT * SUB_PER_BKT)       // 3136
#define SGRID_H (SGRID / 2)                // 1568 (split for profiler visibility)
#define SUBCAP  2816                       // mean 2041, +17 sigma slack

#define NXW2 (N_NODES * 32)                // xcvt items (float4 = 2 bf162 pairs)
#define NW1  (128 * 640)                   // wcvt items
#define NW2  (2 * 128 * 128)               // wcvt2 items

typedef __attribute__((ext_vector_type(8))) short short8;
typedef __attribute__((ext_vector_type(4))) float floatx4;

// ---- fused prep: xcvt (float4) + wcvt + wcvt2 + cursor init, ONE launch ---
__global__ __launch_bounds__(256) void prep_kernel(
    const float* __restrict__ x, uint* __restrict__ xb,
    const float* __restrict__ bases, const float* __restrict__ loopw,
    unsigned short* __restrict__ wT,
    const float* __restrict__ ngnn_w, unsigned short* __restrict__ wT2,
    int* __restrict__ gcursor, int do_x) {
    int idx = blockIdx.x * 256 + threadIdx.x;
    if (do_x) {
        if (idx < NXW2) {                      // x (fp32) -> xb, 2 pairs/thread
            float4 v = *(const float4*)(x + 4 * (size_t)idx);
            __hip_bfloat162 h0 = __float22bfloat162_rn(make_float2(v.x, v.y));
            __hip_bfloat162 h1 = __float22bfloat162_rn(make_float2(v.z, v.w));
            uint2 o = make_uint2(*(uint*)&h0, *(uint*)&h1);
            ((uint2*)xb)[idx] = o;
            return;
        }
        idx -= NXW2;
    }
    if (idx < NW1) {                           // wT[n][k]
        int n = idx / 640, k = idx % 640;
        float v = (k < 512) ? bases[(size_t)k * 128 + n]
                            : loopw[(size_t)(k - 512) * 128 + n];
        __hip_bfloat16 h = __float2bfloat16(v);
        wT[idx] = *(unsigned short*)&h;
        return;
    }
    idx -= NW1;
    if (idx < NW2) {                           // wT2[l][n][k]
        int l = idx >> 14, rem = idx & 16383;
        int n = rem >> 7, k = rem & 127;
        float v = ngnn_w[(size_t)l * 16384 + (size_t)k * 128 + n];
        __hip_bfloat16 h = __float2bfloat16(v);
        wT2[idx] = *(unsigned short*)&h;
        return;
    }
    idx -= NW2;
    if (idx < NBKT) gcursor[idx] = idx * BKT_CAP;
}

// ---- pass 1: partition edges into coarse dst-buckets (coalesced writes) ---
// record = src(17b) | dst_low(7b)<<17 | r(3b)<<24
// v2: int4 edge loads (4 edges per load instruction, 8 iterations).
// E_EDGES % 4 == 0 so an aligned int4 never crosses a relation boundary;
// tail chunk (RE % P1_CHUNK = 2048) is int4-aligned so `e < RE` guards all 4.
__global__ __launch_bounds__(256) void p1_kernel(
    const int* __restrict__ src, const int* __restrict__ dst,
    int* __restrict__ gcursor, int* __restrict__ ebuf2) {
    __shared__ int hist[NBKT];
    __shared__ int cnt2[NBKT];
    __shared__ int basebkt[NBKT];
    __shared__ int lofs[NBKT];
    __shared__ int aux[256];
    __shared__ int recs[P1_CHUNK];           // 32 KB
    __shared__ unsigned short bb[P1_CHUNK];  // 16 KB
    int t = threadIdx.x;
    for (int i = t; i < NBKT; i += 256) { hist[i] = 0; cnt2[i] = 0; }
    __syncthreads();

    int e0 = blockIdx.x * P1_CHUNK;
    int rec[P1_EPT];
    int bkt[P1_EPT];
#pragma unroll
    for (int j = 0; j < P1_EPT / 4; ++j) {
        int e = e0 + j * (P1_TPB * 4) + t * 4;   // coalesced int4
        if (e < RE) {
            int4 d4 = *(const int4*)(dst + e);
            int4 s4 = *(const int4*)(src + e);
            int r = e / E_EDGES;                 // same r for all 4 lanes' elems
            int dd[4] = {d4.x, d4.y, d4.z, d4.w};
            int ss[4] = {s4.x, s4.y, s4.z, s4.w};
#pragma unroll
            for (int q = 0; q < 4; ++q) {
                int ix = j * 4 + q;
                bkt[ix] = dd[q] >> 7;
                rec[ix] = ss[q] | ((dd[q] & 127) << 17) | (r << 24);
                atomicAdd(&hist[bkt[ix]], 1);    // native int ds_add
            }
        } else {
#pragma unroll
            for (int q = 0; q < 4; ++q) bkt[j * 4 + q] = -1;
        }
    }
    __syncthreads();

    // exclusive scan of hist[784]: 4 consecutive per thread + Hillis-Steele
    int k0 = t * 4;
    int c0 = (k0 + 0 < NBKT) ? hist[k0 + 0] : 0;
    int c1 = (k0 + 1 < NBKT) ? hist[k0 + 1] : 0;
    int c2 = (k0 + 2 < NBKT) ? hist[k0 + 2] : 0;
    int c3 = (k0 + 3 < NBKT) ? hist[k0 + 3] : 0;
    int s1 = c0 + c1, s2 = s1 + c2, s3 = s2 + c3;
    aux[t] = s3;
    __syncthreads();
    int vv = s3;
    for (int off = 1; off < 256; off <<= 1) {
        int yv = (t >= off) ? aux[t - off] : 0;
        __syncthreads();
        vv += yv;
        aux[t] = vv;
        __syncthreads();
    }
    int total = aux[255];
    int texcl = vv - s3;
    if (k0 + 0 < NBKT) lofs[k0 + 0] = texcl;
    if (k0 + 1 < NBKT) lofs[k0 + 1] = texcl + c0;
    if (k0 + 2 < NBKT) lofs[k0 + 2] = texcl + s1;
    if (k0 + 3 < NBKT) lofs[k0 + 3] = texcl + s2;
    __syncthreads();
    for (int i = t; i < NBKT; i += 256) {
        int hv = hist[i];
        basebkt[i] = (hv > 0) ? atomicAdd(&gcursor[i], hv) : 0;
    }
    __syncthreads();

    // reorder records into bucket-contiguous LDS slots
#pragma unroll
    for (int i = 0; i < P1_EPT; ++i) {
        if (bkt[i] >= 0) {
            int p = lofs[bkt[i]] + atomicAdd(&cnt2[bkt[i]], 1);
            recs[p] = rec[i];
            bb[p] = (unsigned short)bkt[i];
        }
    }
    __syncthreads();

    // writeout: consecutive i are mostly same-bucket runs
    for (int i = t; i < total; i += 256) {
        int b = bb[i];
        int p2 = basebkt[b] + (i - lofs[b]);
        if (p2 < (b + 1) * BKT_CAP) ebuf2[p2] = recs[i];
    }
}

// ---- fused sort+gather (R9 structure, proven 262 us) ---------------------
// 512 thr (8 waves), 4 WGs/CU (~25 KB LDS). id = blockIdx.x + blk_base:
// id = sub*784 + bucket; the 4 sub-WGs of one bucket are congruent mod 8
// (784 % 8 == 0) -> same XCD. Split into 2 launches of 1568 WGs purely for
// rocprof top-5 visibility of the OTHER kernels (threshold 262 -> ~131 us).
template <bool XB>
__global__ __launch_bounds__(512, 8) void agg3_kernel(
    const float* __restrict__ x,
    const uint*  __restrict__ xb,          // [N][64] bf162 pairs
    const int*   __restrict__ gcursor,
    const int*   __restrict__ ebuf2,
    const float* __restrict__ w_comp,
    __hip_bfloat162* __restrict__ y,       // [N][256] bf162
    int blk_base) {
    __shared__ int raw[SUBCAP];            // 11 KB
    __shared__ int sorted[SUBCAP];         // 11 KB (head doubles as scan aux)
    __shared__ int cursors[256];
    __shared__ int segbeg[256];
    __shared__ int nraw;
    const int t = threadIdx.x;
    const int id = blockIdx.x + blk_base;
    const int bucket = id % NBKT;          // co-XCD mapping for the 4 sub-WGs
    const int sub    = id / NBKT;

    int cnt = gcursor[bucket] - bucket * BKT_CAP;
    if (cnt > BKT_CAP) cnt = BKT_CAP;
    const int* brec = ebuf2 + (size_t)bucket * BKT_CAP;
    if (t < 256) cursors[t] = 0;
    if (t == 0) nraw = 0;
    __syncthreads();

    const int lane = t & 63;
    const unsigned long long lmask = (1ull << lane) - 1ull;

    // single global pass: compact matching records into raw[] + histogram
    for (int i0 = 0; i0 < cnt; i0 += 512) {
        int i = i0 + t;
        int rec = (i < cnt) ? brec[i] : 0;
        bool match = (i < cnt) && ((((rec >> 17) & 127) >> 5) == sub);
        unsigned long long mask = __ballot(match);
        int base = 0;
        if (lane == 0) base = atomicAdd(&nraw, (int)__popcll(mask));
        base = __shfl(base, 0);
        if (match) {
            int p = base + (int)__popcll(mask & lmask);
            if (p < SUBCAP) {
                raw[p] = rec;
                int key = ((rec >> 17) & 31) * 8 + ((rec >> 24) & 7);
                atomicAdd(&cursors[key], 1);
            }
        }
    }
    __syncthreads();
    int n = nraw; if (n > SUBCAP) n = SUBCAP;

    // exclusive scan of 256 degrees (aux aliases sorted[0..511])
    int deg = (t < 256) ? cursors[t] : 0;
    int* aux = sorted;
    aux[t] = deg;
    __syncthreads();
    int vv = deg;
    for (int off = 1; off < 256; off <<= 1) {
        int yv = (t >= off && t < 256) ? aux[t - off] : 0;
        __syncthreads();
        vv += yv;
        aux[t] = vv;
        __syncthreads();
    }
    if (t < 256) {
        cursors[t] = vv - deg;
        segbeg[t]  = vv - deg;
    }
    __syncthreads();

    // in-LDS scatter to sorted order (src ids only)
    for (int i = t; i < n; i += 512) {
        int rec = raw[i];
        int key = ((rec >> 17) & 31) * 8 + ((rec >> 24) & 7);
        int pos = atomicAdd(&cursors[key], 1);   // ds_add_rtn_u32
        sorted[pos] = rec & 0x1FFFF;
    }
    __syncthreads();

    // gather: wave owns 4 nodes; per (node,r) segment sum then basis fold
    const int wid = t >> 6;
    const float* xp  = x + 2 * lane;
    const uint*  xbp = xb + lane;
    for (int nn = 0; nn < 4; ++nn) {
        int nl = wid * 4 + nn;                   // 0..31 within sub-bucket
        int node = bucket * 128 + sub * 32 + nl;
        int key0 = nl * 8;
        float2 acc[B_BASES];
#pragma unroll
        for (int b = 0; b < B_BASES; ++b) acc[b] = make_float2(0.f, 0.f);
#pragma unroll
        for (int r = 0; r < R_REL; ++r) {
            int b0 = segbeg[key0 + r];
            int e0 = cursors[key0 + r];      // post-scatter == segment end
            int d = e0 - b0;
            float inv = 1.0f / (float)(d > 1 ? d : 1);
            float ax = 0.f, ay = 0.f;
            int i = b0;
            if (XB) {
                for (; i + 7 < e0; i += 8) {     // 8 loads in flight
                    int s0 = sorted[i],     s1 = sorted[i + 1];
                    int s2 = sorted[i + 2], s3 = sorted[i + 3];
                    int s4 = sorted[i + 4], s5 = sorted[i + 5];
                    int s6 = sorted[i + 6], s7 = sorted[i + 7];
                    uint u0 = xbp[(size_t)s0 * 64];
                    uint u1 = xbp[(size_t)s1 * 64];
                    uint u2 = xbp[(size_t)s2 * 64];
                    uint u3 = xbp[(size_t)s3 * 64];
                    uint u4 = xbp[(size_t)s4 * 64];
                    uint u5 = xbp[(size_t)s5 * 64];
                    uint u6 = xbp[(size_t)s6 * 64];
                    uint u7 = xbp[(size_t)s7 * 64];
                    ax += ((__uint_as_float(u0 << 16) + __uint_as_float(u1 << 16))
                         + (__uint_as_float(u2 << 16) + __uint_as_float(u3 << 16)))
                        + ((__uint_as_float(u4 << 16) + __uint_as_float(u5 << 16))
                         + (__uint_as_float(u6 << 16) + __uint_as_float(u7 << 16)));
                    ay += ((__uint_as_float(u0 & 0xFFFF0000u) + __uint_as_float(u1 & 0xFFFF0000u))
                         + (__uint_as_float(u2 & 0xFFFF0000u) + __uint_as_float(u3 & 0xFFFF0000u)))
                        + ((__uint_as_float(u4 & 0xFFFF0000u) + __uint_as_float(u5 & 0xFFFF0000u))
                         + (__uint_as_float(u6 & 0xFFFF0000u) + __uint_as_float(u7 & 0xFFFF0000u)));
                }
            }
            for (; i + 3 < e0; i += 4) {
                int s0 = sorted[i], s1 = sorted[i + 1], s2 = sorted[i + 2], s3 = sorted[i + 3];
                if (XB) {
                    uint u0 = xbp[(size_t)s0 * 64];
                    uint u1 = xbp[(size_t)s1 * 64];
                    uint u2 = xbp[(size_t)s2 * 64];
                    uint u3 = xbp[(size_t)s3 * 64];
                    ax += (__uint_as_float(u0 << 16) + __uint_as_float(u1 << 16))
                        + (__uint_as_float(u2 << 16) + __uint_as_float(u3 << 16));
                    ay += (__uint_as_float(u0 & 0xFFFF0000u) + __uint_as_float(u1 & 0xFFFF0000u))
                        + (__uint_as_float(u2 & 0xFFFF0000u) + __uint_as_float(u3 & 0xFFFF0000u));
                } else {
                    float2 a = *(const float2*)(xp + (size_t)s0 * D_FEAT);
                    float2 b = *(const float2*)(xp + (size_t)s1 * D_FEAT);
                    float2 cc = *(const float2*)(xp + (size_t)s2 * D_FEAT);
                    float2 d2 = *(const float2*)(xp + (size_t)s3 * D_FEAT);
                    ax += (a.x + b.x) + (cc.x + d2.x);
                    ay += (a.y + b.y) + (cc.y + d2.y);
                }
            }
            for (; i < e0; ++i) {
                int s = sorted[i];
                if (XB) {
                    uint u = xbp[(size_t)s * 64];
                    ax += __uint_as_float(u << 16);
                    ay += __uint_as_float(u & 0xFFFF0000u);
                } else {
                    float2 a = *(const float2*)(xp + (size_t)s * D_FEAT);
                    ax += a.x; ay += a.y;
                }
            }
#pragma unroll
            for (int b = 0; b < B_BASES; ++b) {
                float coef = w_comp[r * B_BASES + b] * inv;
                acc[b].x = fmaf(coef, ax, acc[b].x);
                acc[b].y = fmaf(coef, ay, acc[b].y);
            }
        }
        if (node < N_NODES) {
#pragma unroll
            for (int b = 0; b < B_BASES; ++b)
                y[(size_t)node * 256 + b * 64 + lane] = __float22bfloat162_rn(acc[b]);
        }
    }
}

// ---- fused MLP v2: M=32 rows/wave (each B-load feeds 2 MFMAs) ------------
#define TPAD 136
template <bool XB>
__global__ __launch_bounds__(256) void fused_mlp(
    const short* __restrict__ y,            // [N][512] bf16
    const float* __restrict__ x,            // [N][128] fp32
    const uint*  __restrict__ xb,           // [N][64] bf162 pairs
    const unsigned short* __restrict__ wT,  // [128][640] bf16, n-major
    const float* __restrict__ bias,
    const unsigned short* __restrict__ wT2, // [2][128][128] bf16, n-major
    float* __restrict__ out) {              // [N][128] fp32
    __shared__ short tile[4][32][TPAD];     // 34.8 KB
    const int wave = threadIdx.x >> 6;
    const int lane = threadIdx.x & 63;
    const int quad = lane >> 4;
    const int l16  = lane & 15;
    const int rbase = blockIdx.x * 128 + wave * 32;
    int r0 = rbase + l16;      if (r0 >= N_NODES) r0 = N_NODES - 1;
    int r1 = rbase + 16 + l16; if (r1 >= N_NODES) r1 = N_NODES - 1;
    short (*tl)[TPAD] = tile[wave];
    const int koff = quad * 8;

    floatx4 acc0[8], acc1[8];
#pragma unroll
    for (int nt = 0; nt < 8; ++nt) {
        acc0[nt] = (floatx4){0.f, 0.f, 0.f, 0.f};
        acc1[nt] = (floatx4){0.f, 0.f, 0.f, 0.f};
    }

    // ---- layer 0: [y | x] @ wT^T, K=640; one B-load feeds both row-groups
    const short* y0 = y + (size_t)r0 * 512;
    const short* y1 = y + (size_t)r1 * 512;
    for (int ks = 0; ks < 16; ++ks) {
        int k0 = ks * 32 + koff;
        short8 a0 = *(const short8*)(y0 + k0);
        short8 a1 = *(const short8*)(y1 + k0);
#pragma unroll
        for (int nt = 0; nt < 8; ++nt) {
            int n = nt * 16 + l16;
            short8 b = *(const short8*)((const short*)wT + (size_t)n * 640 + k0);
            acc0[nt] = __builtin_amdgcn_mfma_f32_16x16x32_bf16(a0, b, acc0[nt], 0, 0, 0);
            acc1[nt] = __builtin_amdgcn_mfma_f32_16x16x32_bf16(a1, b, acc1[nt], 0, 0, 0);
        }
    }
    if (XB) {
        const short* xb0 = (const short*)xb + (size_t)r0 * 128;
        const short* xb1 = (const short*)xb + (size_t)r1 * 128;
#pragma unroll
        for (int ks = 0; ks < 4; ++ks) {
            int kl = ks * 32 + koff;
            short8 a0 = *(const short8*)(xb0 + kl);
            short8 a1 = *(const short8*)(xb1 + kl);
#pragma unroll
            for (int nt = 0; nt < 8; ++nt) {
                int n = nt * 16 + l16;
                short8 b = *(const short8*)((const short*)wT + (size_t)n * 640 + 512 + kl);
                acc0[nt] = __builtin_amdgcn_mfma_f32_16x16x32_bf16(a0, b, acc0[nt], 0, 0, 0);
                acc1[nt] = __builtin_amdgcn_mfma_f32_16x16x32_bf16(a1, b, acc1[nt], 0, 0, 0);
            }
        }
    } else {
        const float* x0 = x + (size_t)r0 * 128;
        const float* x1 = x + (size_t)r1 * 128;
#pragma unroll
        for (int ks = 0; ks < 4; ++ks) {
            int kl = ks * 32 + koff;
            union { short8 s; uint u[4]; } ua0, ua1;
            {
                float4 fa = *(const float4*)(x0 + kl);
                float4 fb = *(const float4*)(x0 + kl + 4);
                __hip_bfloat162 h0 = __float22bfloat162_rn(make_float2(fa.x, fa.y));
                __hip_bfloat162 h1 = __float22bfloat162_rn(make_float2(fa.z, fa.w));
                __hip_bfloat162 h2 = __float22bfloat162_rn(make_float2(fb.x, fb.y));
                __hip_bfloat162 h3 = __float22bfloat162_rn(make_float2(fb.z, fb.w));
                ua0.u[0] = *(uint*)&h0; ua0.u[1] = *(uint*)&h1;
                ua0.u[2] = *(uint*)&h2; ua0.u[3] = *(uint*)&h3;
            }
            {
                float4 fa = *(const float4*)(x1 + kl);
                float4 fb = *(const float4*)(x1 + kl + 4);
                __hip_bfloat162 h0 = __float22bfloat162_rn(make_float2(fa.x, fa.y));
                __hip_bfloat162 h1 = __float22bfloat162_rn(make_float2(fa.z, fa.w));
                __hip_bfloat162 h2 = __float22bfloat162_rn(make_float2(fb.x, fb.y));
                __hip_bfloat162 h3 = __float22bfloat162_rn(make_float2(fb.z, fb.w));
                ua1.u[0] = *(uint*)&h0; ua1.u[1] = *(uint*)&h1;
                ua1.u[2] = *(uint*)&h2; ua1.u[3] = *(uint*)&h3;
            }
#pragma unroll
            for (int nt = 0; nt < 8; ++nt) {
                int n = nt * 16 + l16;
                short8 b = *(const short8*)((const short*)wT + (size_t)n * 640 + 512 + kl);
                acc0[nt] = __builtin_amdgcn_mfma_f32_16x16x32_bf16(ua0.s, b, acc0[nt], 0, 0, 0);
                acc1[nt] = __builtin_amdgcn_mfma_f32_16x16x32_bf16(ua1.s, b, acc1[nt], 0, 0, 0);
            }
        }
    }

    // relu(+bias) -> LDS tile (C-layout write; tile is wave-local)
#pragma unroll
    for (int nt = 0; nt < 8; ++nt) {
        float bs = bias[nt * 16 + l16];
#pragma unroll
        for (int i = 0; i < 4; ++i) {
            int row = quad * 4 + i;
            float v0 = fmaxf(acc0[nt][i] + bs, 0.f);
            float v1 = fmaxf(acc1[nt][i] + bs, 0.f);
            __hip_bfloat16 h0 = __float2bfloat16(v0);
            __hip_bfloat16 h1 = __float2bfloat16(v1);
            tl[row][nt * 16 + l16]      = *(short*)&h0;
            tl[16 + row][nt * 16 + l16] = *(short*)&h1;
        }
    }
    __syncthreads();

    // ---- NGNN layers: K=128 each, A from LDS tile ----
#pragma unroll
    for (int l = 0; l < 2; ++l) {
        const unsigned short* wl = wT2 + l * 16384;
        short8 af0[4], af1[4];
#pragma unroll
        for (int ks = 0; ks < 4; ++ks) {
            af0[ks] = *(const short8*)&tl[l16][ks * 32 + koff];
            af1[ks] = *(const short8*)&tl[16 + l16][ks * 32 + koff];
        }
        floatx4 ac0[8], ac1[8];
#pragma unroll
        for (int nt = 0; nt < 8; ++nt) {
            ac0[nt] = (floatx4){0.f, 0.f, 0.f, 0.f};
            ac1[nt] = (floatx4){0.f, 0.f, 0.f, 0.f};
        }
#pragma unroll
        for (int ks = 0; ks < 4; ++ks) {
            int k0 = ks * 32 + koff;
#pragma unroll
            for (int nt = 0; nt < 8; ++nt) {
                int n = nt * 16 + l16;
                short8 b = *(const short8*)((const short*)wl + (size_t)n * 128 + k0);
                ac0[nt] = __builtin_amdgcn_mfma_f32_16x16x32_bf16(af0[ks], b, ac0[nt], 0, 0, 0);
                ac1[nt] = __builtin_amdgcn_mfma_f32_16x16x32_bf16(af1[ks], b, ac1[nt], 0, 0, 0);
            }
        }
        if (l == 0) {
            __syncthreads();   // all af reads done before overwrite
#pragma unroll
            for (int nt = 0; nt < 8; ++nt)
#pragma unroll
                for (int i = 0; i < 4; ++i) {
                    int row = quad * 4 + i;
                    float v0 = fmaxf(ac0[nt][i], 0.f);
                    float v1 = fmaxf(ac1[nt][i], 0.f);
                    __hip_bfloat16 h0 = __float2bfloat16(v0);
                    __hip_bfloat16 h1 = __float2bfloat16(v1);
                    tl[row][nt * 16 + l16]      = *(short*)&h0;
                    tl[16 + row][nt * 16 + l16] = *(short*)&h1;
                }
            __syncthreads();
        } else {
#pragma unroll
            for (int nt = 0; nt < 8; ++nt) {
                int n = nt * 16 + l16;
#pragma unroll
                for (int i = 0; i < 4; ++i) {
                    int m0 = rbase + quad * 4 + i;
                    int m1 = rbase + 16 + quad * 4 + i;
                    if (m0 < N_NODES)
                        out[(size_t)m0 * D_FEAT + n] = fmaxf(ac0[nt][i], 0.f);
                    if (m1 < N_NODES)
                        out[(size_t)m1 * D_FEAT + n] = fmaxf(ac1[nt][i], 0.f);
                }
            }
        }
    }
}

extern "C" void kernel_launch(void* const* d_in, const int* in_sizes, int n_in,
                              void* d_out, int out_size, void* d_ws, size_t ws_size,
                              hipStream_t stream) {
    const float* x           = (const float*)d_in[0];
    const int*   edge_src    = (const int*)d_in[1];
    const int*   edge_dst    = (const int*)d_in[2];
    const float* w_comp      = (const float*)d_in[3];
    const float* bases       = (const float*)d_in[4];
    const float* loop_weight = (const float*)d_in[5];
    const float* h_bias      = (const float*)d_in[6];
    const float* ngnn_w      = (const float*)d_in[7];
    float* out = (float*)d_out;

    // workspace layout (~131.6 MB base; +25.6 MB optional xb)
    char* ws = (char*)d_ws;
    size_t off = 0;
    __hip_bfloat162* y = (__hip_bfloat162*)(ws + off);
    off += (size_t)N_NODES * 512 * 2;              // 102.4 MB
    int* ebuf2 = (int*)(ws + off);                 // 784*9216*4 = 28.9 MB
    off += (size_t)NBKT * BKT_CAP * 4;
    int* gcursor = (int*)(ws + off);
    off += 4096;
    unsigned short* wT = (unsigned short*)(ws + off);
    off += (size_t)128 * 640 * 2;                  // 160 KB
    unsigned short* wT2 = (unsigned short*)(ws + off);
    off += (size_t)2 * 128 * 128 * 2;              // 64 KB
    uint* xb = (uint*)(ws + off);
    size_t xb_bytes = (size_t)N_NODES * 64 * 4;    // 25.6 MB
    const bool use_bf16_x = (ws_size >= off + xb_bytes);   // ws_size constant across calls

    // 0) fused prep: xcvt + wcvt + wcvt2 + cursor init (one launch)
    int prep_items = (use_bf16_x ? NXW2 : 0) + NW1 + NW2 + NBKT;
    prep_kernel<<<(prep_items + 255) / 256, 256, 0, stream>>>(
        x, xb, bases, loop_weight, wT, ngnn_w, wT2, gcursor, use_bf16_x ? 1 : 0);

    // 1) bucket partition (int4 edge loads)
    p1_kernel<<<P1_NWG, P1_TPB, 0, stream>>>(edge_src, edge_dst, gcursor, ebuf2);

    // 2) fused filter + LDS-sort + gather -> y. Split into 2 launches so the
    //    rocprof top-5 threshold drops to ~131 us (profiler visibility of
    //    p1 / fused_mlp); mapping preserved via blk_base.
    if (use_bf16_x) {
        agg3_kernel<true><<<SGRID_H, 512, 0, stream>>>(x, xb, gcursor, ebuf2, w_comp, y, 0);
        agg3_kernel<true><<<SGRID_H, 512, 0, stream>>>(x, xb, gcursor, ebuf2, w_comp, y, SGRID_H);
    } else {
        agg3_kernel<false><<<SGRID_H, 512, 0, stream>>>(x, nullptr, gcursor, ebuf2, w_comp, y, 0);
        agg3_kernel<false><<<SGRID_H, 512, 0, stream>>>(x, nullptr, gcursor, ebuf2, w_comp, y, SGRID_H);
    }

    // 3) fused MLP: gemm_big + ngnn0 + ngnn1, M=32 rows/wave
    const int MLP_GRID = (N_NODES + 127) / 128;    // 782
    if (use_bf16_x)
        fused_mlp<true><<<MLP_GRID, 256, 0, stream>>>(
            (const short*)y, x, xb, wT, h_bias, wT2, out);
    else
        fused_mlp<false><<<MLP_GRID, 256, 0, stream>>>(
            (const short*)y, x, nullptr, wT, h_bias, wT2, out);
}